// Round 19
// baseline (219.261 us; speedup 1.0000x reference)
//
#include <hip/hip_runtime.h>

#define B_ 2
#define L_ 2048
#define DM 1024
#define H_ 16
#define DK 64
#define ROWS (B_*L_)   // 4096
#define BK 32
#define LDT 40         // LDS row stride for fallback k1 A-tile (80B, 2-way banks)

typedef _Float16 f16x8 __attribute__((ext_vector_type(8)));
typedef __fp16   fp16v2 __attribute__((ext_vector_type(2)));
typedef __fp16   fp16v4 __attribute__((ext_vector_type(4)));
typedef float    f32x4 __attribute__((ext_vector_type(4)));
typedef unsigned short us8 __attribute__((ext_vector_type(8)));
typedef unsigned short us4v __attribute__((ext_vector_type(4)));

__device__ __forceinline__ unsigned short f2h(float f) {
    _Float16 h = (_Float16)f;
    return __builtin_bit_cast(unsigned short, h);
}
__device__ __forceinline__ float h2f(unsigned short u) {
    return (float)__builtin_bit_cast(_Float16, u);
}
__device__ __forceinline__ f16x8 ld8h(const unsigned short* p) {
    return *reinterpret_cast<const f16x8*>(p);
}
__device__ __forceinline__ us8 cvt_us8(float4 a, float4 b) {
    us8 u;
    u[0] = f2h(a.x); u[1] = f2h(a.y); u[2] = f2h(a.z); u[3] = f2h(a.w);
    u[4] = f2h(b.x); u[5] = f2h(b.y); u[6] = f2h(b.z); u[7] = f2h(b.w);
    return u;
}

#define MFMA(a, b, c) __builtin_amdgcn_mfma_f32_16x16x32_f16((a), (b), (c), 0, 0, 0)

// async 16B global -> LDS (DMA). LDS dest must be linear (base + lane*16).
#define AS1 __attribute__((address_space(1)))
#define AS3 __attribute__((address_space(3)))
__device__ __forceinline__ void glds16(const void* g, void* l) {
    __builtin_amdgcn_global_load_lds((const AS1 unsigned int*)g,
                                     (AS3 unsigned int*)l, 16, 0, 0);
}

// ---------------------------------------------------------------------------
// kprep3: fused  (a) w_proj f32->fp16 convert        [blocks 0..511]
//                (b) per-head weight transpose       [blocks 512..1279]
//                (c) q,k,v f32->fp16 bulk convert    [blocks 1280..7423]
// (c) only launched on the fast path (ws >= 56MB). All parts independent.
// W_k pre-scaled by log2(e): k2 softmax runs in exp2 domain.
// ---------------------------------------------------------------------------
__global__ __launch_bounds__(256) void kprep3(
    const float* __restrict__ wproj, unsigned short* __restrict__ wph,
    const float* __restrict__ wq,
    const float* __restrict__ wk,
    const float* __restrict__ wv,
    unsigned short* __restrict__ wt,
    const float* __restrict__ q, const float* __restrict__ k,
    const float* __restrict__ v, unsigned short* __restrict__ qkvh)
{
    int bxg = blockIdx.x;
    if (bxg < 512) {
        size_t i = ((size_t)bxg * 256 + threadIdx.x) * 8;
        const float4* s4 = (const float4*)(wproj + i);
        *(us8*)(wph + i) = cvt_us8(s4[0], s4[1]);
        return;
    }
    if (bxg >= 1280) {                      // qkv bulk convert (fast path only)
        int bx = bxg - 1280;                // 0..6143
        int which = bx >> 11, rem = bx & 2047;
        const float* src = (which == 0) ? q : (which == 1) ? k : v;
        size_t i = ((size_t)rem * 256 + threadIdx.x) * 8;
        const float4* s4 = (const float4*)(src + i);
        *(us8*)(qkvh + (size_t)which * ROWS * DM + i) = cvt_us8(s4[0], s4[1]);
        return;
    }
    __shared__ unsigned short tile[64][65];
    int bx = bxg - 512;
    int which = bx / (H_ * 16);
    int rem   = bx % (H_ * 16);
    int h  = rem >> 4;
    int db = (rem & 15) * 64;
    const float* src = (which == 0) ? wq : (which == 1) ? wk : wv;
    float scale = (which == 1) ? 1.44269504f : 1.0f;

    int t = threadIdx.x;
    int r = t >> 2;
    int c = (t & 3) * 16;
    const float4* sp = (const float4*)(src + ((size_t)(h * DM + db + r)) * DK + c);
    #pragma unroll
    for (int i4 = 0; i4 < 4; i4++) {
        float4 f = sp[i4];
        tile[r][c + i4 * 4 + 0] = f2h(f.x * scale);
        tile[r][c + i4 * 4 + 1] = f2h(f.y * scale);
        tile[r][c + i4 * 4 + 2] = f2h(f.z * scale);
        tile[r][c + i4 * 4 + 3] = f2h(f.w * scale);
    }
    __syncthreads();

    int n   = t >> 2;
    int d16 = (t & 3) * 16;
    __align__(16) unsigned short ov[16];
    #pragma unroll
    for (int i = 0; i < 16; i++) ov[i] = tile[d16 + i][n];
    size_t off = (((size_t)which * H_ + h) * DK + n) * DM + db + d16;
    *(us8*)(wt + off)     = *(us8*)&ov[0];
    *(us8*)(wt + off + 8) = *(us8*)&ov[8];
}

// ---------------------------------------------------------------------------
// K1 fast path, round-19 form: SAME 128x128 tile / 768 blocks / staging as
// the proven round-12 kernel, but 8 waves per block (512 threads): per-CU
// staging and barriers unchanged, per-wave MFMA halves (acc[2][4]),
// waves/CU 12 -> 24. (Round-17's tile-halving trap avoided: tile constant.)
// ---------------------------------------------------------------------------
__global__ __launch_bounds__(512) void k1_proj_fp16(
    const unsigned short* __restrict__ qkvh,  // fp16 [3][ROWS][DM]
    const unsigned short* __restrict__ wt,    // fp16 [3][1024 n][1024 d]
    unsigned short* __restrict__ qh,          // fp16 [H][ROWS][DK]
    unsigned short* __restrict__ kh,          // fp16 [H][ROWS][DK] (log2e-scaled)
    unsigned short* __restrict__ vt)          // fp16 [H][DK][ROWS]
{
    __shared__ __align__(16) unsigned short sA[128 * BK];   // 8 KB
    __shared__ __align__(16) unsigned short sB[128 * BK];   // 8 KB

    int bxr = blockIdx.x;
    int bx  = (bxr & 7) * 96 + (bxr >> 3); // 768 blocks, 96/XCD, bijective
    int which = bx >> 8;           // 0..2
    int rem   = bx & 255;
    int mbase = (rem >> 3) * 128;  // 32 m-tiles
    int nbase = (rem & 7) * 128;   // 8 n-tiles

    const unsigned short* Ag = qkvh + (size_t)which * ROWS * DM;
    const unsigned short* Bg = wt + (size_t)which * DM * DM;

    int t = threadIdx.x;                    // 0..511
    int wave = t >> 6, lane = t & 63, quad = lane >> 4, l16 = lane & 15;
    int wm = (wave >> 1) * 32, wn = (wave & 1) * 64;  // 4x2 grid of 32x64

    // staging: 512 16B-chunks per tile (128 rows x 4 slots), 1 chunk/thread.
    const unsigned short* gA0 = Ag + (size_t)(mbase + (t >> 2)) * DM + (t & 3) * 8;
    const unsigned short* gB0 = Bg + (size_t)(nbase + (t >> 2)) * DM + (t & 3) * 8;
    unsigned short* lA0 = &sA[(size_t)t * 8];
    unsigned short* lB0 = &sB[(size_t)t * 8];

    f32x4 acc[2][4];
    #pragma unroll
    for (int mi = 0; mi < 2; mi++)
        #pragma unroll
        for (int ni = 0; ni < 4; ni++) acc[mi][ni] = (f32x4)0.0f;

    for (int step = 0; step < 32; step++) {
        if (step) __syncthreads();          // prior frag reads done
        glds16(gA0, lA0);
        glds16(gB0, lB0);
        gA0 += BK; gB0 += BK;
        __syncthreads();                    // drains vmcnt(0): tile ready

        f16x8 aF[2], bF[4];
        #pragma unroll
        for (int mi = 0; mi < 2; mi++)
            aF[mi] = *(const f16x8*)&sA[(wm + mi * 16 + l16) * BK + quad * 8];
        #pragma unroll
        for (int ni = 0; ni < 4; ni++)
            bF[ni] = *(const f16x8*)&sB[(wn + ni * 16 + l16) * BK + quad * 8];
        __builtin_amdgcn_s_setprio(1);
        #pragma unroll
        for (int mi = 0; mi < 2; mi++)
            #pragma unroll
            for (int ni = 0; ni < 4; ni++)
                acc[mi][ni] = MFMA(aF[mi], bF[ni], acc[mi][ni]);
        __builtin_amdgcn_s_setprio(0);
    }

    int h = (nbase >> 6) + (wave & 1);      // wave's 64-col span = one head
    if (which < 2) {
        unsigned short* OUT = ((which == 0) ? qh : kh) + (size_t)h * ROWS * DK;
        #pragma unroll
        for (int mi = 0; mi < 2; mi++)
            #pragma unroll
            for (int ni = 0; ni < 4; ni++)
                #pragma unroll
                for (int r = 0; r < 4; r++) {
                    int row = mbase + wm + mi * 16 + quad * 4 + r;
                    OUT[(size_t)row * DK + ni * 16 + l16] = f2h(acc[mi][ni][r]);
                }
    } else {
        unsigned short* OUT = vt + (size_t)h * DK * ROWS;
        #pragma unroll
        for (int mi = 0; mi < 2; mi++)
            #pragma unroll
            for (int ni = 0; ni < 4; ni++) {
                int dk   = ni * 16 + l16;
                int rowb = mbase + wm + mi * 16 + quad * 4;
                us4v pk;
                pk[0] = f2h(acc[mi][ni][0]); pk[1] = f2h(acc[mi][ni][1]);
                pk[2] = f2h(acc[mi][ni][2]); pk[3] = f2h(acc[mi][ni][3]);
                *(us4v*)(OUT + (size_t)dk * ROWS + rowb) = pk;
            }
    }
}

// ---------------------------------------------------------------------------
// K1 fallback (ws < 56MB; not taken on this harness): round-9 form unchanged.
// ---------------------------------------------------------------------------
__global__ __launch_bounds__(256) void k1_proj_qkv(
    const float* __restrict__ q,
    const float* __restrict__ k,
    const float* __restrict__ v,
    const unsigned short* __restrict__ wt,
    unsigned short* __restrict__ qh,
    unsigned short* __restrict__ kh,
    unsigned short* __restrict__ vt)
{
    __shared__ __align__(16) unsigned short sA[128 * LDT];
    __shared__ __align__(16) unsigned short sB[128 * BK];

    int bxr = blockIdx.x;
    int bx  = (bxr & 7) * 96 + (bxr >> 3); // 768 blocks, 96/XCD, bijective
    int which = bx >> 8;
    int rem   = bx & 255;
    int mbase = (rem >> 3) * 128;
    int nbase = (rem & 7) * 128;

    const float* Ag = (which == 0) ? q : (which == 1) ? k : v;
    const unsigned short* Bg = wt + (size_t)which * DM * DM;

    int t = threadIdx.x;
    int wave = t >> 6, lane = t & 63, quad = lane >> 4, l16 = lane & 15;
    int wm = (wave >> 1) * 64, wn = (wave & 1) * 64;

    int ar0 = t >> 2,         ac0 = t & 3;
    int ar1 = (256 + t) >> 2, ac1 = t & 3;
    const float* pA0 = Ag + (size_t)(mbase + ar0) * DM + ac0 * 8;
    const float* pA1 = Ag + (size_t)(mbase + ar1) * DM + ac1 * 8;
    const unsigned short* gB0 = Bg + (size_t)(nbase + (t >> 2)) * DM + (t & 3) * 8;
    const unsigned short* gB1 = gB0 + (size_t)64 * DM;
    unsigned short* wA0 = &sA[ar0 * LDT + ac0 * 8];
    unsigned short* wA1 = &sA[ar1 * LDT + ac1 * 8];
    unsigned short* lB0 = &sB[(size_t)t * 8];
    unsigned short* lB1 = &sB[(size_t)(256 + t) * 8];

    f32x4 acc[4][4];
    #pragma unroll
    for (int mi = 0; mi < 4; mi++)
        #pragma unroll
        for (int ni = 0; ni < 4; ni++) acc[mi][ni] = (f32x4)0.0f;

    float4 rA0a = *(const float4*)pA0, rA0b = *(const float4*)(pA0 + 4);
    float4 rA1a = *(const float4*)pA1, rA1b = *(const float4*)(pA1 + 4);

    for (int step = 0; step < 32; step++) {
        if (step) __syncthreads();
        *(us8*)wA0 = cvt_us8(rA0a, rA0b);
        *(us8*)wA1 = cvt_us8(rA1a, rA1b);
        glds16(gB0, lB0); glds16(gB1, lB1);
        gB0 += BK; gB1 += BK;
        __syncthreads();                    // drains vmcnt(0) + LDS writes
        if (step < 31) {
            pA0 += BK; pA1 += BK;
            rA0a = *(const float4*)pA0; rA0b = *(const float4*)(pA0 + 4);
            rA1a = *(const float4*)pA1; rA1b = *(const float4*)(pA1 + 4);
        }
        f16x8 aF[4], bF[4];
        #pragma unroll
        for (int mi = 0; mi < 4; mi++)
            aF[mi] = *(const f16x8*)&sA[(wm + mi * 16 + l16) * LDT + quad * 8];
        #pragma unroll
        for (int ni = 0; ni < 4; ni++)
            bF[ni] = *(const f16x8*)&sB[(wn + ni * 16 + l16) * BK + quad * 8];
        __builtin_amdgcn_s_setprio(1);
        #pragma unroll
        for (int mi = 0; mi < 4; mi++)
            #pragma unroll
            for (int ni = 0; ni < 4; ni++)
                acc[mi][ni] = MFMA(aF[mi], bF[ni], acc[mi][ni]);
        __builtin_amdgcn_s_setprio(0);
    }

    int h = (nbase >> 6) + (wave & 1);
    if (which < 2) {
        unsigned short* OUT = ((which == 0) ? qh : kh) + (size_t)h * ROWS * DK;
        #pragma unroll
        for (int mi = 0; mi < 4; mi++)
            #pragma unroll
            for (int ni = 0; ni < 4; ni++)
                #pragma unroll
                for (int r = 0; r < 4; r++) {
                    int row = mbase + wm + mi * 16 + quad * 4 + r;
                    OUT[(size_t)row * DK + ni * 16 + l16] = f2h(acc[mi][ni][r]);
                }
    } else {
        unsigned short* OUT = vt + (size_t)h * DK * ROWS;
        #pragma unroll
        for (int mi = 0; mi < 4; mi++)
            #pragma unroll
            for (int ni = 0; ni < 4; ni++) {
                int dk   = ni * 16 + l16;
                int rowb = mbase + wm + mi * 16 + quad * 4;
                us4v pk;
                pk[0] = f2h(acc[mi][ni][0]); pk[1] = f2h(acc[mi][ni][1]);
                pk[2] = f2h(acc[mi][ni][2]); pk[3] = f2h(acc[mi][ni][3]);
                *(us4v*)(OUT + (size_t)dk * ROWS + rowb) = pk;
            }
    }
}

// ---------------------------------------------------------------------------
// K2: flash attention — round-16 form EXACT, FROZEN (proven 62.6-64.5us):
// round-8 per-wave code, 8-wave/128-row blocks, grid 512.
// ---------------------------------------------------------------------------
__global__ __launch_bounds__(512) void k2_attn(
    const unsigned short* __restrict__ qh,   // fp16 [H][ROWS][DK]
    const unsigned short* __restrict__ kh,   // fp16 [H][ROWS][DK] (log2e-scaled)
    const unsigned short* __restrict__ vt,   // fp16 [H][DK][ROWS]
    unsigned short* __restrict__ x2)         // fp16 [ROWS][DM]
{
    __shared__ __align__(16) unsigned short ktile[2][64][64];  // 16 KB
    __shared__ __align__(16) unsigned short vtile[2][64][64];  // 16 KB
    __shared__ __align__(16) unsigned short pld[8][16][64];    // 16 KB

    int bx = blockIdx.x;                    // 512 blocks
    int xcd = bx & 7;
    int loc = bx >> 3;                      // 0..63
    int hb  = xcd * 4 + (loc >> 4);         // 4 hb per xcd
    int qt  = loc & 15;                     // 16 q-tiles of 128 rows
    int h = hb >> 1, b = hb & 1;
    int qbase = qt * 128;

    const unsigned short* qhp = qh + ((size_t)h * ROWS + b * L_) * DK;
    const unsigned short* khp = kh + ((size_t)h * ROWS + b * L_) * DK;
    const unsigned short* vtp = vt + (size_t)h * DK * ROWS + b * L_;

    int wave = threadIdx.x >> 6, lane = threadIdx.x & 63;
    int quad = lane >> 4, l16 = lane & 15;
    int t = threadIdx.x;                    // 0..511
    int g8 = (l16 & 7) * 8;                 // elem-level XOR for this lane

    int c0 = t, key0 = c0 >> 3, ss0 = ((c0 & 7) ^ (key0 & 7)) * 8;
    const unsigned short* kg0 = khp + (size_t)key0 * DK + ss0;
    const unsigned short* vg0 = vtp + (size_t)key0 * ROWS + ss0;
    unsigned short* kl0[2] = { &ktile[0][0][0] + c0 * 8, &ktile[1][0][0] + c0 * 8 };
    unsigned short* vl0[2] = { &vtile[0][0][0] + c0 * 8, &vtile[1][0][0] + c0 * 8 };

    // prologue: stage kt=0 into buffer 0
    glds16(kg0, kl0[0]);
    glds16(vg0, vl0[0]);

    int qrow = qbase + wave * 16 + l16;
    f16x8 qb0 = ld8h(qhp + (size_t)qrow * DK + quad * 8);
    f16x8 qb1 = ld8h(qhp + (size_t)qrow * DK + 32 + quad * 8);

    float m_i = -1e30f, l_i = 0.0f;
    f32x4 o[4];
    #pragma unroll
    for (int nt = 0; nt < 4; nt++) o[nt] = (f32x4)0.0f;

    __syncthreads();                        // drains the prologue DMA

#define K2_STEP(KT, CUR)                                                      \
    {                                                                         \
        if ((KT) < 31) {                                                      \
            size_t ko = (size_t)((KT) + 1) * 64 * DK;                         \
            size_t vo = (size_t)((KT) + 1) * 64;                              \
            glds16(kg0 + ko, kl0[(CUR) ^ 1]);                                 \
            glds16(vg0 + vo, vl0[(CUR) ^ 1]);                                 \
        }                                                                     \
        f32x4 s[4];                                                           \
        _Pragma("unroll")                                                     \
        for (int nt = 0; nt < 4; nt++) s[nt] = (f32x4)0.0f;                   \
        __builtin_amdgcn_s_setprio(1);                                        \
        _Pragma("unroll")                                                     \
        for (int nt = 0; nt < 4; nt++) {                                      \
            const unsigned short* kr = &ktile[CUR][nt * 16 + l16][0];         \
            f16x8 ka0 = *(const f16x8*)(kr + ((quad * 8) ^ g8));              \
            f16x8 ka1 = *(const f16x8*)(kr + ((32 + quad * 8) ^ g8));         \
            s[nt] = MFMA(ka0, qb0, s[nt]);                                    \
            s[nt] = MFMA(ka1, qb1, s[nt]);                                    \
        }                                                                     \
        __builtin_amdgcn_s_setprio(0);                                        \
        float pm[4];                                                          \
        _Pragma("unroll")                                                     \
        for (int nt = 0; nt < 4; nt++) {                                      \
            float a = fmaxf(s[nt][0], s[nt][1]);                              \
            float c2 = fmaxf(s[nt][2], s[nt][3]);                             \
            pm[nt] = fmaxf(a, c2);                                            \
        }                                                                     \
        float mx = fmaxf(fmaxf(pm[0], pm[1]), fmaxf(pm[2], pm[3]));           \
        mx = fmaxf(mx, __shfl_xor(mx, 16));                                   \
        mx = fmaxf(mx, __shfl_xor(mx, 32));                                   \
        if (!__all(mx - m_i <= 11.0f)) {                                      \
            float mnew  = fmaxf(m_i, mx);                                     \
            float alpha = __builtin_amdgcn_exp2f(m_i - mnew);                 \
            l_i *= alpha;                                                     \
            _Pragma("unroll")                                                 \
            for (int r = 0; r < 4; r++) {                                     \
                float av = __shfl(alpha, quad * 4 + r);                       \
                _Pragma("unroll")                                             \
                for (int nt = 0; nt < 4; nt++) o[nt][r] *= av;                \
            }                                                                 \
            m_i = mnew;                                                       \
        }                                                                     \
        float ps[4];                                                          \
        _Pragma("unroll")                                                     \
        for (int nt = 0; nt < 4; nt++) {                                      \
            float e0 = __builtin_amdgcn_exp2f(s[nt][0] - m_i);                \
            float e1 = __builtin_amdgcn_exp2f(s[nt][1] - m_i);                \
            float e2 = __builtin_amdgcn_exp2f(s[nt][2] - m_i);                \
            float e3 = __builtin_amdgcn_exp2f(s[nt][3] - m_i);                \
            s[nt][0] = e0; s[nt][1] = e1; s[nt][2] = e2; s[nt][3] = e3;       \
            ps[nt] = (e0 + e1) + (e2 + e3);                                   \
        }                                                                     \
        float rs = (ps[0] + ps[1]) + (ps[2] + ps[3]);                         \
        rs += __shfl_xor(rs, 16);                                             \
        rs += __shfl_xor(rs, 32);                                             \
        l_i += rs;                                                            \
        _Pragma("unroll")                                                     \
        for (int nt = 0; nt < 4; nt++) {                                      \
            fp16v2 p01 = __builtin_amdgcn_cvt_pkrtz(s[nt][0], s[nt][1]);      \
            fp16v2 p23 = __builtin_amdgcn_cvt_pkrtz(s[nt][2], s[nt][3]);      \
            fp16v4 pk4 = __builtin_shufflevector(p01, p23, 0, 1, 2, 3);       \
            *(fp16v4*)&pld[wave][l16][(nt * 16 + quad * 4) ^ g8] = pk4;       \
        }                                                                     \
        __builtin_amdgcn_s_setprio(1);                                        \
        _Pragma("unroll")                                                     \
        for (int kk = 0; kk < 2; kk++) {                                      \
            f16x8 pa = *(const f16x8*)&pld[wave][l16][(kk * 32 + quad * 8) ^ g8];\
            _Pragma("unroll")                                                 \
            for (int nt = 0; nt < 4; nt++) {                                  \
                const unsigned short* vr = &vtile[CUR][nt * 16 + l16][0];     \
                f16x8 vb = *(const f16x8*)(vr + ((kk * 32 + quad * 8) ^ g8)); \
                o[nt] = MFMA(pa, vb, o[nt]);                                  \
            }                                                                 \
        }                                                                     \
        __builtin_amdgcn_s_setprio(0);                                        \
        __syncthreads();                                                      \
    }

    for (int kt2 = 0; kt2 < 32; kt2 += 2) {
        K2_STEP(kt2,     0)
        K2_STEP(kt2 + 1, 1)
    }
#undef K2_STEP

    float linv = 1.0f / l_i;
    #pragma unroll
    for (int r = 0; r < 4; r++) {
        float lv = __shfl(linv, quad * 4 + r);
        int row = qbase + wave * 16 + quad * 4 + r;
        #pragma unroll
        for (int nt = 0; nt < 4; nt++) {
            int col = nt * 16 + l16;
            float qv = h2f(qhp[(size_t)row * DK + col]);
            float val = o[nt][r] * lv * qv;
            x2[((size_t)b * L_ + row) * DM + h * DK + col] = f2h(val);
        }
    }
}

// ---------------------------------------------------------------------------
// K3: output projection, round-19 form: same 128x128 tile / 256 blocks /
// staging as round-12, but 8 waves per block (512 threads): waves/CU 4 -> 8
// (was 1 block/CU = 1 wave/SIMD, the worst latency-hiding in the pipeline).
// ---------------------------------------------------------------------------
__global__ __launch_bounds__(512) void k3_out_proj(
    const unsigned short* __restrict__ x2,     // fp16 [ROWS][DM]
    const unsigned short* __restrict__ wph,    // fp16 [DM][DM] (row = out dim)
    const float* __restrict__ bias,
    float* __restrict__ out)
{
    __shared__ __align__(16) unsigned short sA[128 * BK];
    __shared__ __align__(16) unsigned short sB[128 * BK];

    int bxr = blockIdx.x;
    int bx  = (bxr & 7) * 32 + (bxr >> 3); // 256 blocks, 32/XCD, bijective
    int mbase = (bx >> 3) * 128;
    int nbase = (bx & 7) * 128;

    int t = threadIdx.x;                    // 0..511
    int wave = t >> 6, lane = t & 63, quad = lane >> 4, l16 = lane & 15;
    int wm = (wave >> 1) * 32, wn = (wave & 1) * 64;  // 4x2 grid of 32x64

    const unsigned short* gA0 = x2  + (size_t)(mbase + (t >> 2)) * DM + (t & 3) * 8;
    const unsigned short* gB0 = wph + (size_t)(nbase + (t >> 2)) * DM + (t & 3) * 8;
    unsigned short* lA0 = &sA[(size_t)t * 8];
    unsigned short* lB0 = &sB[(size_t)t * 8];

    f32x4 acc[2][4];
    #pragma unroll
    for (int mi = 0; mi < 2; mi++)
        #pragma unroll
        for (int ni = 0; ni < 4; ni++) acc[mi][ni] = (f32x4)0.0f;

    for (int step = 0; step < 32; step++) {
        if (step) __syncthreads();
        glds16(gA0, lA0);
        glds16(gB0, lB0);
        gA0 += BK; gB0 += BK;
        __syncthreads();

        f16x8 aF[2], bF[4];
        #pragma unroll
        for (int mi = 0; mi < 2; mi++)
            aF[mi] = *(const f16x8*)&sA[(wm + mi * 16 + l16) * BK + quad * 8];
        #pragma unroll
        for (int ni = 0; ni < 4; ni++)
            bF[ni] = *(const f16x8*)&sB[(wn + ni * 16 + l16) * BK + quad * 8];
        __builtin_amdgcn_s_setprio(1);
        #pragma unroll
        for (int mi = 0; mi < 2; mi++)
            #pragma unroll
            for (int ni = 0; ni < 4; ni++)
                acc[mi][ni] = MFMA(aF[mi], bF[ni], acc[mi][ni]);
        __builtin_amdgcn_s_setprio(0);
    }

    float bv[4];
    #pragma unroll
    for (int ni = 0; ni < 4; ni++) bv[ni] = bias[nbase + wn + ni * 16 + l16];

    #pragma unroll
    for (int mi = 0; mi < 2; mi++)
        #pragma unroll
        for (int ni = 0; ni < 4; ni++)
            #pragma unroll
            for (int r = 0; r < 4; r++) {
                int row = mbase + wm + mi * 16 + quad * 4 + r;
                int col = nbase + wn + ni * 16 + l16;
                out[(size_t)row * DM + col] = acc[mi][ni][r] + bv[ni];
            }
}

// ---------------------------------------------------------------------------
extern "C" void kernel_launch(void* const* d_in, const int* in_sizes, int n_in,
                              void* d_out, int out_size, void* d_ws, size_t ws_size,
                              hipStream_t stream)
{
    const float* q     = (const float*)d_in[0];
    const float* k     = (const float*)d_in[1];
    const float* v     = (const float*)d_in[2];
    const float* wqs   = (const float*)d_in[3];
    const float* wks   = (const float*)d_in[4];
    const float* wvs   = (const float*)d_in[5];
    const float* wproj = (const float*)d_in[6];
    const float* bproj = (const float*)d_in[7];
    float* out = (float*)d_out;

    char* ws = (char*)d_ws;
    #define MB (size_t)(1024 * 1024)
    unsigned short* wt   = (unsigned short*)(ws);            // 0-6 MB  (kprep3 -> k1)
    unsigned short* wph  = (unsigned short*)(ws + 6  * MB);  // 6-8    (kprep3 -> k3)
    unsigned short* qh   = (unsigned short*)(ws + 8  * MB);  // 8-16   (k1 -> k2)
    unsigned short* kh   = (unsigned short*)(ws + 16 * MB);  // 16-24  (k1 -> k2)
    unsigned short* vt   = (unsigned short*)(ws + 24 * MB);  // 24-32  (k1 -> k2)
    unsigned short* x2   = (unsigned short*)(ws + 32 * MB);  // 32-40  (k2 -> k3)
    unsigned short* qkvh = (unsigned short*)(ws + 32 * MB);  // 32-56  (kprep3 -> k1)
    // qkvh overlaps x2: qkvh is dead before k2 writes x2 (stream-ordered).

    bool fast = (ws_size >= 56 * MB);
    int prep_blocks = fast ? (512 + 3 * H_ * 16 + 3 * 2048) : (512 + 3 * H_ * 16);
    kprep3<<<dim3(prep_blocks), dim3(256), 0, stream>>>(
        wproj, wph, wqs, wks, wvs, wt, q, k, v, qkvh);

    if (fast) {
        k1_proj_fp16<<<dim3(3 * 32 * 8), dim3(512), 0, stream>>>(qkvh, wt, qh, kh, vt);
    } else {
        k1_proj_qkv<<<dim3(3 * 32 * 8), dim3(256), 0, stream>>>(q, k, v, wt, qh, kh, vt);
    }
    k2_attn<<<dim3(H_ * B_ * 16), dim3(512), 0, stream>>>(qh, kh, vt, x2);
    k3_out_proj<<<dim3(32 * 8), dim3(512), 0, stream>>>(x2, wph, bproj, out);
}

// Round 20
// 217.157 us; speedup vs baseline: 1.0097x; 1.0097x over previous
//
#include <hip/hip_runtime.h>

#define B_ 2
#define L_ 2048
#define DM 1024
#define H_ 16
#define DK 64
#define ROWS (B_*L_)   // 4096
#define BK 32
#define LDT 40         // LDS row stride for fallback k1 A-tile (80B, 2-way banks)

typedef _Float16 f16x8 __attribute__((ext_vector_type(8)));
typedef __fp16   fp16v2 __attribute__((ext_vector_type(2)));
typedef __fp16   fp16v4 __attribute__((ext_vector_type(4)));
typedef float    f32x4 __attribute__((ext_vector_type(4)));
typedef unsigned short us8 __attribute__((ext_vector_type(8)));
typedef unsigned short us4v __attribute__((ext_vector_type(4)));

__device__ __forceinline__ unsigned short f2h(float f) {
    _Float16 h = (_Float16)f;
    return __builtin_bit_cast(unsigned short, h);
}
__device__ __forceinline__ float h2f(unsigned short u) {
    return (float)__builtin_bit_cast(_Float16, u);
}
__device__ __forceinline__ f16x8 ld8h(const unsigned short* p) {
    return *reinterpret_cast<const f16x8*>(p);
}
__device__ __forceinline__ us8 cvt_us8(float4 a, float4 b) {
    us8 u;
    u[0] = f2h(a.x); u[1] = f2h(a.y); u[2] = f2h(a.z); u[3] = f2h(a.w);
    u[4] = f2h(b.x); u[5] = f2h(b.y); u[6] = f2h(b.z); u[7] = f2h(b.w);
    return u;
}

#define MFMA(a, b, c) __builtin_amdgcn_mfma_f32_16x16x32_f16((a), (b), (c), 0, 0, 0)

// async 16B global -> LDS (DMA). LDS dest must be linear (base + lane*16).
#define AS1 __attribute__((address_space(1)))
#define AS3 __attribute__((address_space(3)))
__device__ __forceinline__ void glds16(const void* g, void* l) {
    __builtin_amdgcn_global_load_lds((const AS1 unsigned int*)g,
                                     (AS3 unsigned int*)l, 16, 0, 0);
}

// ---------------------------------------------------------------------------
// kprep3: fused  (a) w_proj f32->fp16 convert        [blocks 0..511]
//                (b) per-head weight transpose       [blocks 512..1279]
//                (c) q,k,v f32->fp16 bulk convert    [blocks 1280..7423]
// (c) only launched on the fast path (ws >= 56MB). All parts independent.
// W_k pre-scaled by log2(e): k2 softmax runs in exp2 domain.
// ---------------------------------------------------------------------------
__global__ __launch_bounds__(256) void kprep3(
    const float* __restrict__ wproj, unsigned short* __restrict__ wph,
    const float* __restrict__ wq,
    const float* __restrict__ wk,
    const float* __restrict__ wv,
    unsigned short* __restrict__ wt,
    const float* __restrict__ q, const float* __restrict__ k,
    const float* __restrict__ v, unsigned short* __restrict__ qkvh)
{
    int bxg = blockIdx.x;
    if (bxg < 512) {
        size_t i = ((size_t)bxg * 256 + threadIdx.x) * 8;
        const float4* s4 = (const float4*)(wproj + i);
        *(us8*)(wph + i) = cvt_us8(s4[0], s4[1]);
        return;
    }
    if (bxg >= 1280) {                      // qkv bulk convert (fast path only)
        int bx = bxg - 1280;                // 0..6143
        int which = bx >> 11, rem = bx & 2047;
        const float* src = (which == 0) ? q : (which == 1) ? k : v;
        size_t i = ((size_t)rem * 256 + threadIdx.x) * 8;
        const float4* s4 = (const float4*)(src + i);
        *(us8*)(qkvh + (size_t)which * ROWS * DM + i) = cvt_us8(s4[0], s4[1]);
        return;
    }
    __shared__ unsigned short tile[64][65];
    int bx = bxg - 512;
    int which = bx / (H_ * 16);
    int rem   = bx % (H_ * 16);
    int h  = rem >> 4;
    int db = (rem & 15) * 64;
    const float* src = (which == 0) ? wq : (which == 1) ? wk : wv;
    float scale = (which == 1) ? 1.44269504f : 1.0f;

    int t = threadIdx.x;
    int r = t >> 2;
    int c = (t & 3) * 16;
    const float4* sp = (const float4*)(src + ((size_t)(h * DM + db + r)) * DK + c);
    #pragma unroll
    for (int i4 = 0; i4 < 4; i4++) {
        float4 f = sp[i4];
        tile[r][c + i4 * 4 + 0] = f2h(f.x * scale);
        tile[r][c + i4 * 4 + 1] = f2h(f.y * scale);
        tile[r][c + i4 * 4 + 2] = f2h(f.z * scale);
        tile[r][c + i4 * 4 + 3] = f2h(f.w * scale);
    }
    __syncthreads();

    int n   = t >> 2;
    int d16 = (t & 3) * 16;
    __align__(16) unsigned short ov[16];
    #pragma unroll
    for (int i = 0; i < 16; i++) ov[i] = tile[d16 + i][n];
    size_t off = (((size_t)which * H_ + h) * DK + n) * DM + db + d16;
    *(us8*)(wt + off)     = *(us8*)&ov[0];
    *(us8*)(wt + off + 8) = *(us8*)&ov[8];
}

// ---------------------------------------------------------------------------
// K1 fast path (round-12 exact form, part of the 217.5us best): all-fp16,
// glds16 staging, linear LDS [128][32], XCD-swizzled blockIdx (768 = 8x96).
// Geometry variants tested and rejected: BK=64 (R13, null), 64x128 tile
// (R17, -12us regression: doubles per-CU B staging), 8-wave block (R19,
// null: +33% B-frag LDS reads). This form is the measured optimum.
// ---------------------------------------------------------------------------
__global__ __launch_bounds__(256) void k1_proj_fp16(
    const unsigned short* __restrict__ qkvh,  // fp16 [3][ROWS][DM]
    const unsigned short* __restrict__ wt,    // fp16 [3][1024 n][1024 d]
    unsigned short* __restrict__ qh,          // fp16 [H][ROWS][DK]
    unsigned short* __restrict__ kh,          // fp16 [H][ROWS][DK] (log2e-scaled)
    unsigned short* __restrict__ vt)          // fp16 [H][DK][ROWS]
{
    __shared__ __align__(16) unsigned short sA[128 * BK];
    __shared__ __align__(16) unsigned short sB[128 * BK];

    int bxr = blockIdx.x;
    int bx  = (bxr & 7) * 96 + (bxr >> 3);
    int which = bx >> 8;           // 0..2
    int rem   = bx & 255;
    int mbase = (rem >> 3) * 128;  // 32 m-tiles
    int nbase = (rem & 7) * 128;   // 8 n-tiles

    const unsigned short* Ag = qkvh + (size_t)which * ROWS * DM;
    const unsigned short* Bg = wt + (size_t)which * DM * DM;

    int t = threadIdx.x;
    int wave = t >> 6, lane = t & 63, quad = lane >> 4, l16 = lane & 15;
    int wm = (wave >> 1) * 64, wn = (wave & 1) * 64;

    const unsigned short* gA0 = Ag + (size_t)(mbase + (t >> 2)) * DM + (t & 3) * 8;
    const unsigned short* gA1 = gA0 + (size_t)64 * DM;
    const unsigned short* gB0 = Bg + (size_t)(nbase + (t >> 2)) * DM + (t & 3) * 8;
    const unsigned short* gB1 = gB0 + (size_t)64 * DM;
    unsigned short* lA0 = &sA[(size_t)t * 8];
    unsigned short* lA1 = &sA[(size_t)(256 + t) * 8];
    unsigned short* lB0 = &sB[(size_t)t * 8];
    unsigned short* lB1 = &sB[(size_t)(256 + t) * 8];

    f32x4 acc[4][4];
    #pragma unroll
    for (int mi = 0; mi < 4; mi++)
        #pragma unroll
        for (int ni = 0; ni < 4; ni++) acc[mi][ni] = (f32x4)0.0f;

    for (int step = 0; step < 32; step++) {
        if (step) __syncthreads();          // prior frag reads done
        glds16(gA0, lA0); glds16(gA1, lA1);
        glds16(gB0, lB0); glds16(gB1, lB1);
        gA0 += BK; gA1 += BK; gB0 += BK; gB1 += BK;
        __syncthreads();                    // drains vmcnt(0): tile ready

        f16x8 aF[4], bF[4];
        #pragma unroll
        for (int mi = 0; mi < 4; mi++)
            aF[mi] = *(const f16x8*)&sA[(wm + mi * 16 + l16) * BK + quad * 8];
        #pragma unroll
        for (int ni = 0; ni < 4; ni++)
            bF[ni] = *(const f16x8*)&sB[(wn + ni * 16 + l16) * BK + quad * 8];
        __builtin_amdgcn_s_setprio(1);
        #pragma unroll
        for (int mi = 0; mi < 4; mi++)
            #pragma unroll
            for (int ni = 0; ni < 4; ni++)
                acc[mi][ni] = MFMA(aF[mi], bF[ni], acc[mi][ni]);
        __builtin_amdgcn_s_setprio(0);
    }

    int h = (nbase >> 6) + (wave & 1);      // wave's 64-col span = one head
    if (which < 2) {
        unsigned short* OUT = ((which == 0) ? qh : kh) + (size_t)h * ROWS * DK;
        #pragma unroll
        for (int mi = 0; mi < 4; mi++)
            #pragma unroll
            for (int ni = 0; ni < 4; ni++)
                #pragma unroll
                for (int r = 0; r < 4; r++) {
                    int row = mbase + wm + mi * 16 + quad * 4 + r;
                    OUT[(size_t)row * DK + ni * 16 + l16] = f2h(acc[mi][ni][r]);
                }
    } else {
        unsigned short* OUT = vt + (size_t)h * DK * ROWS;
        #pragma unroll
        for (int mi = 0; mi < 4; mi++)
            #pragma unroll
            for (int ni = 0; ni < 4; ni++) {
                int dk   = ni * 16 + l16;
                int rowb = mbase + wm + mi * 16 + quad * 4;
                us4v pk;
                pk[0] = f2h(acc[mi][ni][0]); pk[1] = f2h(acc[mi][ni][1]);
                pk[2] = f2h(acc[mi][ni][2]); pk[3] = f2h(acc[mi][ni][3]);
                *(us4v*)(OUT + (size_t)dk * ROWS + rowb) = pk;
            }
    }
}

// ---------------------------------------------------------------------------
// K1 fallback (ws < 56MB; not taken on this harness): round-9 form unchanged.
// ---------------------------------------------------------------------------
__global__ __launch_bounds__(256) void k1_proj_qkv(
    const float* __restrict__ q,
    const float* __restrict__ k,
    const float* __restrict__ v,
    const unsigned short* __restrict__ wt,
    unsigned short* __restrict__ qh,
    unsigned short* __restrict__ kh,
    unsigned short* __restrict__ vt)
{
    __shared__ __align__(16) unsigned short sA[128 * LDT];
    __shared__ __align__(16) unsigned short sB[128 * BK];

    int bxr = blockIdx.x;
    int bx  = (bxr & 7) * 96 + (bxr >> 3); // 768 blocks, 96/XCD, bijective
    int which = bx >> 8;
    int rem   = bx & 255;
    int mbase = (rem >> 3) * 128;
    int nbase = (rem & 7) * 128;

    const float* Ag = (which == 0) ? q : (which == 1) ? k : v;
    const unsigned short* Bg = wt + (size_t)which * DM * DM;

    int t = threadIdx.x;
    int wave = t >> 6, lane = t & 63, quad = lane >> 4, l16 = lane & 15;
    int wm = (wave >> 1) * 64, wn = (wave & 1) * 64;

    int ar0 = t >> 2,         ac0 = t & 3;
    int ar1 = (256 + t) >> 2, ac1 = t & 3;
    const float* pA0 = Ag + (size_t)(mbase + ar0) * DM + ac0 * 8;
    const float* pA1 = Ag + (size_t)(mbase + ar1) * DM + ac1 * 8;
    const unsigned short* gB0 = Bg + (size_t)(nbase + (t >> 2)) * DM + (t & 3) * 8;
    const unsigned short* gB1 = gB0 + (size_t)64 * DM;
    unsigned short* wA0 = &sA[ar0 * LDT + ac0 * 8];
    unsigned short* wA1 = &sA[ar1 * LDT + ac1 * 8];
    unsigned short* lB0 = &sB[(size_t)t * 8];
    unsigned short* lB1 = &sB[(size_t)(256 + t) * 8];

    f32x4 acc[4][4];
    #pragma unroll
    for (int mi = 0; mi < 4; mi++)
        #pragma unroll
        for (int ni = 0; ni < 4; ni++) acc[mi][ni] = (f32x4)0.0f;

    float4 rA0a = *(const float4*)pA0, rA0b = *(const float4*)(pA0 + 4);
    float4 rA1a = *(const float4*)pA1, rA1b = *(const float4*)(pA1 + 4);

    for (int step = 0; step < 32; step++) {
        if (step) __syncthreads();
        *(us8*)wA0 = cvt_us8(rA0a, rA0b);
        *(us8*)wA1 = cvt_us8(rA1a, rA1b);
        glds16(gB0, lB0); glds16(gB1, lB1);
        gB0 += BK; gB1 += BK;
        __syncthreads();                    // drains vmcnt(0) + LDS writes
        if (step < 31) {
            pA0 += BK; pA1 += BK;
            rA0a = *(const float4*)pA0; rA0b = *(const float4*)(pA0 + 4);
            rA1a = *(const float4*)pA1; rA1b = *(const float4*)(pA1 + 4);
        }
        f16x8 aF[4], bF[4];
        #pragma unroll
        for (int mi = 0; mi < 4; mi++)
            aF[mi] = *(const f16x8*)&sA[(wm + mi * 16 + l16) * LDT + quad * 8];
        #pragma unroll
        for (int ni = 0; ni < 4; ni++)
            bF[ni] = *(const f16x8*)&sB[(wn + ni * 16 + l16) * BK + quad * 8];
        __builtin_amdgcn_s_setprio(1);
        #pragma unroll
        for (int mi = 0; mi < 4; mi++)
            #pragma unroll
            for (int ni = 0; ni < 4; ni++)
                acc[mi][ni] = MFMA(aF[mi], bF[ni], acc[mi][ni]);
        __builtin_amdgcn_s_setprio(0);
    }

    int h = (nbase >> 6) + (wave & 1);
    if (which < 2) {
        unsigned short* OUT = ((which == 0) ? qh : kh) + (size_t)h * ROWS * DK;
        #pragma unroll
        for (int mi = 0; mi < 4; mi++)
            #pragma unroll
            for (int ni = 0; ni < 4; ni++)
                #pragma unroll
                for (int r = 0; r < 4; r++) {
                    int row = mbase + wm + mi * 16 + quad * 4 + r;
                    OUT[(size_t)row * DK + ni * 16 + l16] = f2h(acc[mi][ni][r]);
                }
    } else {
        unsigned short* OUT = vt + (size_t)h * DK * ROWS;
        #pragma unroll
        for (int mi = 0; mi < 4; mi++)
            #pragma unroll
            for (int ni = 0; ni < 4; ni++) {
                int dk   = ni * 16 + l16;
                int rowb = mbase + wm + mi * 16 + quad * 4;
                us4v pk;
                pk[0] = f2h(acc[mi][ni][0]); pk[1] = f2h(acc[mi][ni][1]);
                pk[2] = f2h(acc[mi][ni][2]); pk[3] = f2h(acc[mi][ni][3]);
                *(us4v*)(OUT + (size_t)dk * ROWS + rowb) = pk;
            }
    }
}

// ---------------------------------------------------------------------------
// K2: flash attention — round-16 form EXACT, FROZEN (62.6-64.5us across 4
// runs): round-8 per-wave code (2-phase DMA double-buffer, XOR swizzle,
// exp2-domain softmax, defer-max, CUR-unroll, cvt_pkrtz), 8-wave/128-row
// blocks (the single biggest win of the session: TLP 16->24 waves/CU).
// ---------------------------------------------------------------------------
__global__ __launch_bounds__(512) void k2_attn(
    const unsigned short* __restrict__ qh,   // fp16 [H][ROWS][DK]
    const unsigned short* __restrict__ kh,   // fp16 [H][ROWS][DK] (log2e-scaled)
    const unsigned short* __restrict__ vt,   // fp16 [H][DK][ROWS]
    unsigned short* __restrict__ x2)         // fp16 [ROWS][DM]
{
    __shared__ __align__(16) unsigned short ktile[2][64][64];  // 16 KB
    __shared__ __align__(16) unsigned short vtile[2][64][64];  // 16 KB
    __shared__ __align__(16) unsigned short pld[8][16][64];    // 16 KB

    int bx = blockIdx.x;                    // 512 blocks
    int xcd = bx & 7;
    int loc = bx >> 3;                      // 0..63
    int hb  = xcd * 4 + (loc >> 4);         // 4 hb per xcd
    int qt  = loc & 15;                     // 16 q-tiles of 128 rows
    int h = hb >> 1, b = hb & 1;
    int qbase = qt * 128;

    const unsigned short* qhp = qh + ((size_t)h * ROWS + b * L_) * DK;
    const unsigned short* khp = kh + ((size_t)h * ROWS + b * L_) * DK;
    const unsigned short* vtp = vt + (size_t)h * DK * ROWS + b * L_;

    int wave = threadIdx.x >> 6, lane = threadIdx.x & 63;
    int quad = lane >> 4, l16 = lane & 15;
    int t = threadIdx.x;                    // 0..511
    int g8 = (l16 & 7) * 8;                 // elem-level XOR for this lane

    int c0 = t, key0 = c0 >> 3, ss0 = ((c0 & 7) ^ (key0 & 7)) * 8;
    const unsigned short* kg0 = khp + (size_t)key0 * DK + ss0;
    const unsigned short* vg0 = vtp + (size_t)key0 * ROWS + ss0;
    unsigned short* kl0[2] = { &ktile[0][0][0] + c0 * 8, &ktile[1][0][0] + c0 * 8 };
    unsigned short* vl0[2] = { &vtile[0][0][0] + c0 * 8, &vtile[1][0][0] + c0 * 8 };

    // prologue: stage kt=0 into buffer 0
    glds16(kg0, kl0[0]);
    glds16(vg0, vl0[0]);

    int qrow = qbase + wave * 16 + l16;
    f16x8 qb0 = ld8h(qhp + (size_t)qrow * DK + quad * 8);
    f16x8 qb1 = ld8h(qhp + (size_t)qrow * DK + 32 + quad * 8);

    float m_i = -1e30f, l_i = 0.0f;
    f32x4 o[4];
    #pragma unroll
    for (int nt = 0; nt < 4; nt++) o[nt] = (f32x4)0.0f;

    __syncthreads();                        // drains the prologue DMA

#define K2_STEP(KT, CUR)                                                      \
    {                                                                         \
        if ((KT) < 31) {                                                      \
            size_t ko = (size_t)((KT) + 1) * 64 * DK;                         \
            size_t vo = (size_t)((KT) + 1) * 64;                              \
            glds16(kg0 + ko, kl0[(CUR) ^ 1]);                                 \
            glds16(vg0 + vo, vl0[(CUR) ^ 1]);                                 \
        }                                                                     \
        f32x4 s[4];                                                           \
        _Pragma("unroll")                                                     \
        for (int nt = 0; nt < 4; nt++) s[nt] = (f32x4)0.0f;                   \
        __builtin_amdgcn_s_setprio(1);                                        \
        _Pragma("unroll")                                                     \
        for (int nt = 0; nt < 4; nt++) {                                      \
            const unsigned short* kr = &ktile[CUR][nt * 16 + l16][0];         \
            f16x8 ka0 = *(const f16x8*)(kr + ((quad * 8) ^ g8));              \
            f16x8 ka1 = *(const f16x8*)(kr + ((32 + quad * 8) ^ g8));         \
            s[nt] = MFMA(ka0, qb0, s[nt]);                                    \
            s[nt] = MFMA(ka1, qb1, s[nt]);                                    \
        }                                                                     \
        __builtin_amdgcn_s_setprio(0);                                        \
        float pm[4];                                                          \
        _Pragma("unroll")                                                     \
        for (int nt = 0; nt < 4; nt++) {                                      \
            float a = fmaxf(s[nt][0], s[nt][1]);                              \
            float c2 = fmaxf(s[nt][2], s[nt][3]);                             \
            pm[nt] = fmaxf(a, c2);                                            \
        }                                                                     \
        float mx = fmaxf(fmaxf(pm[0], pm[1]), fmaxf(pm[2], pm[3]));           \
        mx = fmaxf(mx, __shfl_xor(mx, 16));                                   \
        mx = fmaxf(mx, __shfl_xor(mx, 32));                                   \
        if (!__all(mx - m_i <= 11.0f)) {                                      \
            float mnew  = fmaxf(m_i, mx);                                     \
            float alpha = __builtin_amdgcn_exp2f(m_i - mnew);                 \
            l_i *= alpha;                                                     \
            _Pragma("unroll")                                                 \
            for (int r = 0; r < 4; r++) {                                     \
                float av = __shfl(alpha, quad * 4 + r);                       \
                _Pragma("unroll")                                             \
                for (int nt = 0; nt < 4; nt++) o[nt][r] *= av;                \
            }                                                                 \
            m_i = mnew;                                                       \
        }                                                                     \
        float ps[4];                                                          \
        _Pragma("unroll")                                                     \
        for (int nt = 0; nt < 4; nt++) {                                      \
            float e0 = __builtin_amdgcn_exp2f(s[nt][0] - m_i);                \
            float e1 = __builtin_amdgcn_exp2f(s[nt][1] - m_i);                \
            float e2 = __builtin_amdgcn_exp2f(s[nt][2] - m_i);                \
            float e3 = __builtin_amdgcn_exp2f(s[nt][3] - m_i);                \
            s[nt][0] = e0; s[nt][1] = e1; s[nt][2] = e2; s[nt][3] = e3;       \
            ps[nt] = (e0 + e1) + (e2 + e3);                                   \
        }                                                                     \
        float rs = (ps[0] + ps[1]) + (ps[2] + ps[3]);                         \
        rs += __shfl_xor(rs, 16);                                             \
        rs += __shfl_xor(rs, 32);                                             \
        l_i += rs;                                                            \
        _Pragma("unroll")                                                     \
        for (int nt = 0; nt < 4; nt++) {                                      \
            fp16v2 p01 = __builtin_amdgcn_cvt_pkrtz(s[nt][0], s[nt][1]);      \
            fp16v2 p23 = __builtin_amdgcn_cvt_pkrtz(s[nt][2], s[nt][3]);      \
            fp16v4 pk4 = __builtin_shufflevector(p01, p23, 0, 1, 2, 3);       \
            *(fp16v4*)&pld[wave][l16][(nt * 16 + quad * 4) ^ g8] = pk4;       \
        }                                                                     \
        __builtin_amdgcn_s_setprio(1);                                        \
        _Pragma("unroll")                                                     \
        for (int kk = 0; kk < 2; kk++) {                                      \
            f16x8 pa = *(const f16x8*)&pld[wave][l16][(kk * 32 + quad * 8) ^ g8];\
            _Pragma("unroll")                                                 \
            for (int nt = 0; nt < 4; nt++) {                                  \
                const unsigned short* vr = &vtile[CUR][nt * 16 + l16][0];     \
                f16x8 vb = *(const f16x8*)(vr + ((kk * 32 + quad * 8) ^ g8)); \
                o[nt] = MFMA(pa, vb, o[nt]);                                  \
            }                                                                 \
        }                                                                     \
        __builtin_amdgcn_s_setprio(0);                                        \
        __syncthreads();                                                      \
    }

    for (int kt2 = 0; kt2 < 32; kt2 += 2) {
        K2_STEP(kt2,     0)
        K2_STEP(kt2 + 1, 1)
    }
#undef K2_STEP

    float linv = 1.0f / l_i;
    #pragma unroll
    for (int r = 0; r < 4; r++) {
        float lv = __shfl(linv, quad * 4 + r);
        int row = qbase + wave * 16 + quad * 4 + r;
        #pragma unroll
        for (int nt = 0; nt < 4; nt++) {
            int col = nt * 16 + l16;
            float qv = h2f(qhp[(size_t)row * DK + col]);
            float val = o[nt][r] * lv * qv;
            x2[((size_t)b * L_ + row) * DM + h * DK + col] = f2h(val);
        }
    }
}

// ---------------------------------------------------------------------------
// K3: output projection — round-12 exact form (linear glds16 LDS + XCD
// swizzle, BK=32, 256 threads). 8-wave variant nulled (R19).
// ---------------------------------------------------------------------------
__global__ __launch_bounds__(256) void k3_out_proj(
    const unsigned short* __restrict__ x2,     // fp16 [ROWS][DM]
    const unsigned short* __restrict__ wph,    // fp16 [DM][DM] (row = out dim)
    const float* __restrict__ bias,
    float* __restrict__ out)
{
    __shared__ __align__(16) unsigned short sA[128 * BK];
    __shared__ __align__(16) unsigned short sB[128 * BK];

    int bxr = blockIdx.x;
    int bx  = (bxr & 7) * 32 + (bxr >> 3); // 256 blocks, 32/XCD, bijective
    int mbase = (bx >> 3) * 128;
    int nbase = (bx & 7) * 128;

    int t = threadIdx.x;
    int wave = t >> 6, lane = t & 63, quad = lane >> 4, l16 = lane & 15;
    int wm = (wave >> 1) * 64, wn = (wave & 1) * 64;

    const unsigned short* gA0 = x2 + (size_t)(mbase + (t >> 2)) * DM + (t & 3) * 8;
    const unsigned short* gA1 = gA0 + (size_t)64 * DM;
    const unsigned short* gB0 = wph + (size_t)(nbase + (t >> 2)) * DM + (t & 3) * 8;
    const unsigned short* gB1 = gB0 + (size_t)64 * DM;
    unsigned short* lA0 = &sA[(size_t)t * 8];
    unsigned short* lA1 = &sA[(size_t)(256 + t) * 8];
    unsigned short* lB0 = &sB[(size_t)t * 8];
    unsigned short* lB1 = &sB[(size_t)(256 + t) * 8];

    f32x4 acc[4][4];
    #pragma unroll
    for (int mi = 0; mi < 4; mi++)
        #pragma unroll
        for (int ni = 0; ni < 4; ni++) acc[mi][ni] = (f32x4)0.0f;

    for (int step = 0; step < 32; step++) {
        if (step) __syncthreads();
        glds16(gA0, lA0); glds16(gA1, lA1);
        glds16(gB0, lB0); glds16(gB1, lB1);
        gA0 += BK; gA1 += BK; gB0 += BK; gB1 += BK;
        __syncthreads();

        f16x8 aF[4], bF[4];
        #pragma unroll
        for (int mi = 0; mi < 4; mi++)
            aF[mi] = *(const f16x8*)&sA[(wm + mi * 16 + l16) * BK + quad * 8];
        #pragma unroll
        for (int ni = 0; ni < 4; ni++)
            bF[ni] = *(const f16x8*)&sB[(wn + ni * 16 + l16) * BK + quad * 8];
        __builtin_amdgcn_s_setprio(1);
        #pragma unroll
        for (int mi = 0; mi < 4; mi++)
            #pragma unroll
            for (int ni = 0; ni < 4; ni++)
                acc[mi][ni] = MFMA(aF[mi], bF[ni], acc[mi][ni]);
        __builtin_amdgcn_s_setprio(0);
    }

    float bv[4];
    #pragma unroll
    for (int ni = 0; ni < 4; ni++) bv[ni] = bias[nbase + wn + ni * 16 + l16];

    #pragma unroll
    for (int mi = 0; mi < 4; mi++)
        #pragma unroll
        for (int ni = 0; ni < 4; ni++)
            #pragma unroll
            for (int r = 0; r < 4; r++) {
                int row = mbase + wm + mi * 16 + quad * 4 + r;
                int col = nbase + wn + ni * 16 + l16;
                out[(size_t)row * DM + col] = acc[mi][ni][r] + bv[ni];
            }
}

// ---------------------------------------------------------------------------
extern "C" void kernel_launch(void* const* d_in, const int* in_sizes, int n_in,
                              void* d_out, int out_size, void* d_ws, size_t ws_size,
                              hipStream_t stream)
{
    const float* q     = (const float*)d_in[0];
    const float* k     = (const float*)d_in[1];
    const float* v     = (const float*)d_in[2];
    const float* wqs   = (const float*)d_in[3];
    const float* wks   = (const float*)d_in[4];
    const float* wvs   = (const float*)d_in[5];
    const float* wproj = (const float*)d_in[6];
    const float* bproj = (const float*)d_in[7];
    float* out = (float*)d_out;

    char* ws = (char*)d_ws;
    #define MB (size_t)(1024 * 1024)
    unsigned short* wt   = (unsigned short*)(ws);            // 0-6 MB  (kprep3 -> k1)
    unsigned short* wph  = (unsigned short*)(ws + 6  * MB);  // 6-8    (kprep3 -> k3)
    unsigned short* qh   = (unsigned short*)(ws + 8  * MB);  // 8-16   (k1 -> k2)
    unsigned short* kh   = (unsigned short*)(ws + 16 * MB);  // 16-24  (k1 -> k2)
    unsigned short* vt   = (unsigned short*)(ws + 24 * MB);  // 24-32  (k1 -> k2)
    unsigned short* x2   = (unsigned short*)(ws + 32 * MB);  // 32-40  (k2 -> k3)
    unsigned short* qkvh = (unsigned short*)(ws + 32 * MB);  // 32-56  (kprep3 -> k1)
    // qkvh overlaps x2: qkvh is dead before k2 writes x2 (stream-ordered).

    bool fast = (ws_size >= 56 * MB);
    int prep_blocks = fast ? (512 + 3 * H_ * 16 + 3 * 2048) : (512 + 3 * H_ * 16);
    kprep3<<<dim3(prep_blocks), dim3(256), 0, stream>>>(
        wproj, wph, wqs, wks, wvs, wt, q, k, v, qkvh);

    if (fast) {
        k1_proj_fp16<<<dim3(3 * 32 * 8), dim3(256), 0, stream>>>(qkvh, wt, qh, kh, vt);
    } else {
        k1_proj_qkv<<<dim3(3 * 32 * 8), dim3(256), 0, stream>>>(q, k, v, wt, qh, kh, vt);
    }
    k2_attn<<<dim3(H_ * B_ * 16), dim3(512), 0, stream>>>(qh, kh, vt, x2);
    k3_out_proj<<<dim3(32 * 8), dim3(256), 0, stream>>>(x2, wph, bproj, out);
}